// Round 5
// baseline (391.941 us; speedup 1.0000x reference)
//
#include <hip/hip_runtime.h>

// EEGGraphClf graph-loss, fused single pass over A. B=64, N=1024, D=16.
//
// loss[b] = 0.2 * [ sum_n deg_n*||f_n||^2 - sum_j f_j . w_j ] / N^2
//         - 0.1 * sum_n log(deg_n + 1e-12) / N
//         + 0.1 * sum_{n,j} A[n,j]^2 / N^2
//   with w_j = sum_n A[n,j] * f_n   (register accumulators, dotted once at end)
//
// 16 blocks/batch, block = 64 rows x 1024 cols, 256 threads, 4 cols/thread.
//
// R4 post-mortem: f-path (s_load/LDS/readlane), nt-flag, depth 2/4/8, and
// 256/512 threads all land ~86-91us @ ~3.1 TB/s -> none were binding. The
// invariant: 8B/lane loads (512B/wave-instr). m13's 6.3 TB/s ceiling used
// 16B/lane. vmcnt counts INSTRUCTIONS, so narrow loads halve in-flight
// bytes at fixed depth and double request-issue work per byte.
// R5 isolates load width: vf4 (1KB/wave-instr) x depth-8 = 8KB in flight
// per wave (~96KB/CU even at 3 waves/SIMD = 10x Little's law @900cy).
// Keep readlane f-cache (zero loop memory ops for f). Live set ~125 regs;
// launch_bounds(256,3) caps at ~170 so the R1 spill (hard 128 cap, live
// ~140 -> 1GB scratch WRITE_SIZE) cannot recur. Spill signature to check:
// WRITE_SIZE must stay ~0.1MB.

#define NN      1024
#define DD      16
#define ROWS    64
#define TPB     256
#define SMOOTHR 0.2f
#define DEGRR   0.1f
#define SPARSR  0.1f
#define EPSV    1e-12f

typedef float vf4 __attribute__((ext_vector_type(4)));

__global__ __launch_bounds__(TPB, 3)
void graph_loss_kernel(const float* __restrict__ A,
                       const float* __restrict__ F,
                       float* __restrict__ out) {
    __shared__ float degq[ROWS][65];     // 16.6 KB, stride 65: 2 lanes/bank reads
    __shared__ float wred[4][2];

    const int tid = threadIdx.x;
    const int bid = blockIdx.x;
    const int b   = bid >> 4;
    const int n0  = (bid & 15) * ROWS;

    const float* __restrict__ Fb = F + (size_t)b * NN * DD;
    const float* __restrict__ Ab = A + ((size_t)b * NN + n0) * NN;

    // ---- per-lane F-row cache: lane l holds F[n0+l][0..15] (16 VGPR) ----
    float fr[16];
    {
        const int lane = tid & 63;
        const vf4* p = (const vf4*)(Fb + (size_t)(n0 + lane) * DD);
        const vf4 t0 = p[0], t1 = p[1], t2 = p[2], t3 = p[3];
        fr[0]=t0.x;  fr[1]=t0.y;  fr[2]=t0.z;  fr[3]=t0.w;
        fr[4]=t1.x;  fr[5]=t1.y;  fr[6]=t1.z;  fr[7]=t1.w;
        fr[8]=t2.x;  fr[9]=t2.y;  fr[10]=t2.z; fr[11]=t2.w;
        fr[12]=t3.x; fr[13]=t3.y; fr[14]=t3.z; fr[15]=t3.w;
    }

    // ---- per-thread state: w[col][k] = 64 VGPR accumulators ----
    float w[4][16];
    #pragma unroll
    for (int c = 0; c < 4; ++c)
        #pragma unroll
        for (int k = 0; k < 16; ++k) w[c][k] = 0.f;

    float sq = 0.f;
    const float* __restrict__ arow = Ab + 4 * tid;
    const int  g       = tid >> 2;           // 4 threads = 16 cols per group
    const bool deglane = (tid & 3) == 0;

    #define LOADR(r) (*(const vf4*)(arow + (size_t)(r) * NN))
    // broadcast F[n0+rr][k] from lane rr of the F-row cache (uniform -> SGPR)
    #define RL(v, l) __builtin_bit_cast(float, \
        __builtin_amdgcn_readlane(__builtin_bit_cast(int, (v)), (l)))
    #define COMPUTE(av, rr)                                                  \
        do {                                                                 \
            float s_ = (av.x + av.y) + (av.z + av.w);                        \
            s_ += __shfl_xor(s_, 1);                                         \
            s_ += __shfl_xor(s_, 2);                                         \
            if (deglane) degq[(rr)][g] = s_;                                 \
            sq += av.x * av.x + av.y * av.y + av.z * av.z + av.w * av.w;     \
            _Pragma("unroll")                                                \
            for (int k = 0; k < 16; ++k) {                                   \
                const float fk = RL(fr[k], (rr));                            \
                w[0][k] += av.x * fk;                                        \
                w[1][k] += av.y * fk;                                        \
                w[2][k] += av.z * fk;                                        \
                w[3][k] += av.w * fk;                                        \
            }                                                                \
        } while (0)

    // ---- prologue: 8-row vf4 A prefetch (8KB/wave in flight) ----
    vf4 a[8];
    #pragma unroll
    for (int i = 0; i < 8; ++i) a[i] = LOADR(i);

    // ---- main loop: 8 rows/iter, zero barriers, only A loads on vmcnt ----
    #pragma unroll 1
    for (int r = 0; r < ROWS - 8; r += 8) {
        #pragma unroll
        for (int i = 0; i < 8; ++i) {
            COMPUTE(a[i], r + i);
            a[i] = LOADR(r + 8 + i);
        }
    }
    // epilogue: rows ROWS-8..ROWS-1
    #pragma unroll
    for (int i = 0; i < 8; ++i) COMPUTE(a[i], ROWS - 8 + i);

    #undef LOADR
    #undef RL
    #undef COMPUTE

    // ---- finalize degrees: deg_n, log(deg_n), deg_n*||f_n||^2 (wave 0) ----
    __syncthreads();
    float lg = 0.f, dfn = 0.f;
    if (tid < ROWS) {
        float s0 = 0.f, s1 = 0.f, s2 = 0.f, s3 = 0.f;   // 4-way ILP split
        #pragma unroll
        for (int i = 0; i < 16; ++i) {
            s0 += degq[tid][4 * i + 0];
            s1 += degq[tid][4 * i + 1];
            s2 += degq[tid][4 * i + 2];
            s3 += degq[tid][4 * i + 3];
        }
        const float s = (s0 + s1) + (s2 + s3);
        lg = logf(s + EPSV);
        float t = 0.f;
        #pragma unroll
        for (int k = 0; k < 16; ++k) t += fr[k] * fr[k];  // lane tid = row n0+tid
        dfn = s * t;
    }

    // ---- dot own columns' features against w (16 vf4 global loads, once) ----
    float dot = 0.f;
    {
        const float* p = Fb + (size_t)(4 * tid) * DD;
        #pragma unroll
        for (int jj = 0; jj < 4; ++jj)
            #pragma unroll
            for (int q = 0; q < 4; ++q) {
                const vf4 f = *(const vf4*)(p + jj * DD + 4 * q);
                dot += f.x * w[jj][4*q+0] + f.y * w[jj][4*q+1]
                     + f.z * w[jj][4*q+2] + f.w * w[jj][4*q+3];
            }
    }

    // ---- block reduction: dot/sq across 4 waves; lg/dfn live in wave 0 ----
    #pragma unroll
    for (int m = 1; m < 64; m <<= 1) {
        dot += __shfl_xor(dot, m);
        sq  += __shfl_xor(sq, m);
        lg  += __shfl_xor(lg, m);
        dfn += __shfl_xor(dfn, m);
    }
    const int wv = tid >> 6;
    if ((tid & 63) == 0) { wred[wv][0] = dot; wred[wv][1] = sq; }
    __syncthreads();
    if (tid == 0) {
        float Dt = 0.f, Q = 0.f;
        #pragma unroll
        for (int i = 0; i < 4; ++i) { Dt += wred[i][0]; Q += wred[i][1]; }
        const float denom = (float)NN * (float)NN;
        const float contrib = SMOOTHR * (dfn - Dt) / denom
                            - DEGRR * lg / (float)NN
                            + SPARSR * Q / denom;
        atomicAdd(out + b, contrib);
    }
}

extern "C" void kernel_launch(void* const* d_in, const int* in_sizes, int n_in,
                              void* d_out, int out_size, void* d_ws, size_t ws_size,
                              hipStream_t stream) {
    const float* A = (const float*)d_in[0];   // out_adj [B,N,N]
    const float* F = (const float*)d_in[1];   // features [B,N,D]
    float* out = (float*)d_out;               // [B]

    const int B = out_size;                   // 64
    (void)hipMemsetAsync(d_out, 0, (size_t)B * sizeof(float), stream);
    graph_loss_kernel<<<dim3(B * (NN / ROWS)), dim3(TPB), 0, stream>>>(A, F, out);
}